// Round 7
// baseline (278.417 us; speedup 1.0000x reference)
//
#include <hip/hip_runtime.h>
#include <hip/hip_fp16.h>

#define NBIN 4096
#define NREP 8        // bin replicas (XCD-aligned via bid&7)
#define SCAP 32       // capacity per replica sub-bin (8*32 = 256 total per bin)
#define OVCAP 65536
#define BPB 4         // bins per k4 block

using f32x4 = __attribute__((ext_vector_type(4))) float;
using i32x4 = __attribute__((ext_vector_type(4))) int;

// coif4 decomposition low-pass filter (24 taps). REC_LO[k]=DEC_LO[23-k], REC_HI[k]=(-1)^k*DEC_LO[k]
__device__ __constant__ float DEC_LO[24] = {
    -1.7849850030882614e-06f, -3.2596802368833675e-06f, 3.1229875865345646e-05f,
    6.233903446100713e-05f, -0.00025997455248771324f, -0.0005890207562443383f,
    0.0012665619292989445f, 0.003751436157278457f, -0.00565828668661072f,
    -0.015211731527946259f, 0.025082261844864097f, 0.03933442712333749f,
    -0.09622044203398798f, -0.06662747426342504f, 0.4343860564914685f,
    0.782238930920499f, 0.41530840703043026f, -0.05607731331675481f,
    -0.08126669968087875f, 0.026682300156053072f, 0.016068943964776348f,
    -0.0073461663276420935f, -0.0016294920126017326f, 0.0008923136685823146f
};

struct PK {
    const float* yl[6];
    const float* yhb[6];   // [C][3][64][w4]
    const float* yha[6];   // [C][3][128][w2]
    float* x1[6];          // [C][128][w2] fp32
    __half* lo2[6];        // [C][256][w2] fp16
    __half* hi2[6];
    __half* planeH[6];     // [256][W][32] fp16 channel-last
    const float* pts;
    const float* ts;
    int* cnt;              // [NREP][NBIN] + ovCnt at cnt[NREP*NBIN]
    int* cum;              // [NBIN][8] cumulative clamped counts (filled by k3)
    float4* binP4;         // [NREP][NBIN][SCAP]
    int* binIdx;           // [NREP][NBIN][SCAP]
    float4* ovP4;          // [OVCAP]
    int* ovIdx;
    int Npts;
};

__device__ __forceinline__ void compute_p4(const float* pts, const float* ts, int p, float* p4) {
    const float sc = (float)(2.0 / (-2.0 * 1.3));
    p4[0] = (pts[p * 3 + 0] - 1.3f) * sc - 1.0f;
    p4[1] = (pts[p * 3 + 1] - 1.3f) * sc - 1.0f;
    p4[2] = (pts[p * 3 + 2] - 1.3f) * sc - 1.0f;
    p4[3] = ts[p] * 2.0f - 1.0f;
}

__device__ __forceinline__ int morton_key(const float* p4) {
    int key = 0;
#pragma unroll
    for (int d = 0; d < 4; ++d) {
        float u = (p4[d] + 1.0f) * 0.5f * 8.0f;
        int ci = (int)u;
        ci = ci < 0 ? 0 : (ci > 7 ? 7 : ci);
#pragma unroll
        for (int b = 0; b < 3; ++b) key |= ((ci >> b) & 1) << (b * 4 + d);
    }
    return key;
}

// ============ K1: idwt level-1 (blocks 0..767) || zero counters (768..896) ========
__global__ __launch_bounds__(256) void k1_l1_zero(PK a) {
    __shared__ struct { float lo[32 * 64], hi[32 * 64]; } sm;
    int bid = blockIdx.x, tid = threadIdx.x;

    if (bid < 768) {
        int rg = bid & 3, c = (bid >> 2) & 31, i = bid >> 7;
        int w4 = (i == 0 || i == 1 || i == 3) ? 64 : 16;
        int lw4 = (w4 == 64) ? 6 : 4;

        const float* llc = a.yl[i] + (size_t)c * 64 * w4;
        const float* lhc = a.yhb[i] + (size_t)(c * 3 + 0) * 64 * w4;
        const float* hlc = a.yhb[i] + (size_t)(c * 3 + 1) * 64 * w4;
        const float* hhc = a.yhb[i] + (size_t)(c * 3 + 2) * 64 * w4;

        for (int idx = tid; idx < (16 << lw4); idx += 256) {
            int mp = idx >> lw4, x = idx & (w4 - 1);
            int m = rg * 16 + mp;
            float lo0 = 0.f, lo1 = 0.f, hi0 = 0.f, hi1 = 0.f;
#pragma unroll
            for (int j = 0; j < 12; ++j) {
                int r = (m - j) & 63;
                int ii = (r << lw4) + x;
                float vll = llc[ii], vlh = lhc[ii], vhl = hlc[ii], vhh = hhc[ii];
                float rl0 = DEC_LO[23 - 2 * j], rl1 = DEC_LO[22 - 2 * j];
                float rh0 = DEC_LO[2 * j],      rh1 = -DEC_LO[2 * j + 1];
                lo0 += rl0 * vll + rh0 * vlh;
                lo1 += rl1 * vll + rh1 * vlh;
                hi0 += rl0 * vhl + rh0 * vhh;
                hi1 += rl1 * vhl + rh1 * vhh;
            }
            sm.lo[((2 * mp) << lw4) + x] = lo0;
            sm.lo[((2 * mp + 1) << lw4) + x] = lo1;
            sm.hi[((2 * mp) << lw4) + x] = hi0;
            sm.hi[((2 * mp + 1) << lw4) + x] = hi1;
        }
        __syncthreads();

        int w2 = w4 * 2;
        float* x1p = a.x1[i] + (size_t)c * 128 * w2;
        for (int idx = tid; idx < (32 << lw4); idx += 256) {
            int yl = idx >> lw4, mcol = idx & (w4 - 1);
            float o0 = 0.f, o1 = 0.f;
#pragma unroll
            for (int j = 0; j < 12; ++j) {
                int r = (mcol - j) & (w4 - 1);
                float vl = sm.lo[(yl << lw4) + r], vh = sm.hi[(yl << lw4) + r];
                o0 += DEC_LO[23 - 2 * j] * vl + DEC_LO[2 * j] * vh;
                o1 += DEC_LO[22 - 2 * j] * vl - DEC_LO[2 * j + 1] * vh;
            }
            *(float2*)(x1p + (size_t)(rg * 32 + yl) * w2 + 2 * mcol) = make_float2(o0, o1);
        }
    } else {
        int idx = (bid - 768) * 256 + tid;
        if (idx <= NREP * NBIN) a.cnt[idx] = 0;   // 8*4096 replica counters + ovCnt
    }
}

// ============ K2: replica scatter (0..511) || idwt level-2 vertical (512..2431, 4 x-outputs/thread, XCD-swizzled) ==========
__global__ __launch_bounds__(256) void k2_v2_scatter(PK a) {
    int bid = blockIdx.x, tid = threadIdx.x;

    if (bid < 512) {
        // Single-pass scatter into replica sub-bins: replica = bid&7 aligns all
        // writers of a given counter/data line to one XCD and cuts per-line
        // atomic serialization 8x. 4-pt batching overlaps atomic latencies.
        // Non-temporal stores: binP4/binIdx are write-once, read-next-kernel —
        // keep them out of L2's hot set.
        const int S = 512 * 256;  // 131072 threads
        int rep = bid & 7;
        int t = bid * 256 + tid;
        for (int base = 0; base < a.Npts; base += 4 * S) {
            float4 q[4];
            int key[4], pi[4], pos[4];
#pragma unroll
            for (int k = 0; k < 4; ++k) {
                int p = base + t + k * S;
                pi[k] = p;
                if (p < a.Npts) {
                    float p4[4];
                    compute_p4(a.pts, a.ts, p, p4);
                    key[k] = morton_key(p4);
                    q[k] = make_float4(p4[0], p4[1], p4[2], p4[3]);
                } else {
                    key[k] = -1;
                }
            }
#pragma unroll
            for (int k = 0; k < 4; ++k)
                if (key[k] >= 0) pos[k] = atomicAdd(&a.cnt[rep * NBIN + key[k]], 1);
#pragma unroll
            for (int k = 0; k < 4; ++k) {
                if (key[k] < 0) continue;
                if (pos[k] < SCAP) {
                    size_t slot = ((size_t)rep * NBIN + key[k]) * SCAP + pos[k];
                    __builtin_nontemporal_store(*(f32x4*)&q[k], (f32x4*)(a.binP4 + slot));
                    __builtin_nontemporal_store(pi[k], a.binIdx + slot);
                } else {
                    int ov = atomicAdd(&a.cnt[NREP * NBIN], 1);
                    if (ov < OVCAP) {
                        __builtin_nontemporal_store(*(f32x4*)&q[k], (f32x4*)(a.ovP4 + ov));
                        __builtin_nontemporal_store(pi[k], a.ovIdx + ov);
                    }
                }
            }
        }
    } else {
        int ib = bid - 512;                 // 0..1919
        ib = (ib & 7) * 240 + (ib >> 3);    // XCD chunk swizzle (bijective: 1920 % 8 == 0)

        const int boff[7] = {0, 512, 1024, 1152, 1664, 1792, 1920};
        int i = 0;
        while (i < 5 && ib >= boff[i + 1]) ++i;
        int lw2 = (i == 0 || i == 1 || i == 3) ? 7 : 5;
        int w2 = 1 << lw2;
        unsigned t = (unsigned)(ib - boff[i]) * 256u + tid;
        unsigned tpc = 32u << lw2;          // threads per channel (w2/4 x-quads * 128 rows)
        unsigned c = t >> (5 + lw2);
        unsigned rem = t & (tpc - 1);
        unsigned m = rem >> (lw2 - 2);
        unsigned x = (rem & (unsigned)((w2 >> 2) - 1)) * 4;
        unsigned hw = 128u << lw2;

        const float* llc = a.x1[i] + (size_t)c * hw;
        const float* lhc = a.yha[i] + (size_t)(c * 3 + 0) * hw;
        const float* hlc = a.yha[i] + (size_t)(c * 3 + 1) * hw;
        const float* hhc = a.yha[i] + (size_t)(c * 3 + 2) * hw;

        float4 acl0 = {0,0,0,0}, acl1 = {0,0,0,0}, ach0 = {0,0,0,0}, ach1 = {0,0,0,0};
#pragma unroll
        for (int j = 0; j < 12; ++j) {
            int r = ((int)m - j) & 127;
            unsigned idx = ((unsigned)r << lw2) + x;
            float4 vll = *(const float4*)(llc + idx);
            float4 vlh = *(const float4*)(lhc + idx);
            float4 vhl = *(const float4*)(hlc + idx);
            float4 vhh = *(const float4*)(hhc + idx);
            float rl0 = DEC_LO[23 - 2 * j], rl1 = DEC_LO[22 - 2 * j];
            float rh0 = DEC_LO[2 * j],      rh1 = -DEC_LO[2 * j + 1];
            acl0.x += rl0 * vll.x + rh0 * vlh.x;  acl0.y += rl0 * vll.y + rh0 * vlh.y;
            acl0.z += rl0 * vll.z + rh0 * vlh.z;  acl0.w += rl0 * vll.w + rh0 * vlh.w;
            acl1.x += rl1 * vll.x + rh1 * vlh.x;  acl1.y += rl1 * vll.y + rh1 * vlh.y;
            acl1.z += rl1 * vll.z + rh1 * vlh.z;  acl1.w += rl1 * vll.w + rh1 * vlh.w;
            ach0.x += rl0 * vhl.x + rh0 * vhh.x;  ach0.y += rl0 * vhl.y + rh0 * vhh.y;
            ach0.z += rl0 * vhl.z + rh0 * vhh.z;  ach0.w += rl0 * vhl.w + rh0 * vhh.w;
            ach1.x += rl1 * vhl.x + rh1 * vhh.x;  ach1.y += rl1 * vhl.y + rh1 * vhh.y;
            ach1.z += rl1 * vhl.z + rh1 * vhh.z;  ach1.w += rl1 * vhl.w + rh1 * vhh.w;
        }
        size_t ob = ((size_t)c * 256 + 2 * m) * w2 + x;
        __half* lp = a.lo2[i] + ob;
        *(__half2*)(lp)          = __floats2half2_rn(acl0.x, acl0.y);
        *(__half2*)(lp + 2)      = __floats2half2_rn(acl0.z, acl0.w);
        *(__half2*)(lp + w2)     = __floats2half2_rn(acl1.x, acl1.y);
        *(__half2*)(lp + w2 + 2) = __floats2half2_rn(acl1.z, acl1.w);
        __half* hpp = a.hi2[i] + ob;
        *(__half2*)(hpp)          = __floats2half2_rn(ach0.x, ach0.y);
        *(__half2*)(hpp + 2)      = __floats2half2_rn(ach0.z, ach0.w);
        *(__half2*)(hpp + w2)     = __floats2half2_rn(ach1.x, ach1.y);
        *(__half2*)(hpp + w2 + 2) = __floats2half2_rn(ach1.z, ach1.w);
    }
}

// ============ K3: idwt l2 horizontal + transpose (0..1535) || cum-prefix table (1536..1551) ========
__global__ __launch_bounds__(256) void k3_ht(PK a) {
    __shared__ struct { __half lo[32 * 130], hi[32 * 130]; } sm;
    int bid = blockIdx.x, tid = threadIdx.x;

    if (bid < 1536) {
        int i = bid >> 8, y = bid & 255;
        int lw2 = (i == 0 || i == 1 || i == 3) ? 7 : 5;
        int w2 = 1 << lw2;
        int stride = w2 + 2;  // fp16 LDS: conflict-free column reads

        for (int idx = tid; idx < (32 << lw2); idx += 256) {
            int c = idx >> lw2, x = idx & (w2 - 1);
            size_t g = ((size_t)c * 256 + y) * w2 + x;
            sm.lo[c * stride + x] = a.lo2[i][g];
            sm.hi[c * stride + x] = a.hi2[i][g];
        }
        __syncthreads();

        int W = 2 * w2;
        __half* orow = a.planeH[i] + (size_t)y * W * 32;
        for (int idx = tid; idx < (32 << lw2); idx += 256) {
            int m = idx >> 5, c = idx & 31;
            float o0 = 0.f, o1 = 0.f;
#pragma unroll
            for (int j = 0; j < 12; ++j) {
                int r2 = m - j; if (r2 < 0) r2 += w2;
                float vl = __half2float(sm.lo[c * stride + r2]);
                float vh = __half2float(sm.hi[c * stride + r2]);
                o0 += DEC_LO[23 - 2 * j] * vl + DEC_LO[2 * j] * vh;
                o1 += DEC_LO[22 - 2 * j] * vl - DEC_LO[2 * j + 1] * vh;
            }
            orow[(2 * m) * 32 + c] = __float2half(o0);
            orow[(2 * m + 1) * 32 + c] = __float2half(o1);
        }
    } else {
        // Compact the 8 scattered replica counters per bin into a contiguous
        // cumulative table: k4 then needs 2 coalesced int4 loads, not 8
        // scattered 4B loads 16KB apart.
        int bin = (bid - 1536) * 256 + tid;
        int c = 0;
#pragma unroll
        for (int r = 0; r < NREP; ++r) {
            int v = a.cnt[r * NBIN + bin];
            c += (v < SCAP ? v : SCAP);
            a.cum[bin * 8 + r] = c;
        }
    }
}

// ============ K4: sampling, 4 bins/block (1024 blocks) + 8 overflow blocks.
// XCD selector = bin bits 8..10 (xh,yh,zh): per-XCD texel footprint ~4.7MB.
// Non-temporal for out/binP4/binIdx/cum so the 15.7MB of plane texels own L2.
union H8 { float4 f4; __half h[8]; };

struct SK {
    const __half* pl[6];
    const float4* binP4;
    const int* binIdx;
    const int* cnt;
    const int* cum;
    const float4* ovP4;
    const int* ovIdx;
    float* out;
};

// Two points' samples interleaved per plane: 8 independent 16B loads in flight
// per step — doubles per-thread MLP on the latency-critical path.
__device__ __forceinline__ void sample_pair(const SK& a,
        const float* p4A, int oA, int chA,
        const float* p4B, int oB, int chB, bool hasB) {
    const int PW[6] = {256, 256, 64, 256, 64, 64};
    const int QI[6] = {0, 0, 3, 1, 3, 3};
    const int RI[6] = {1, 2, 0, 2, 1, 2};
    float accA[8] = {1.f, 1.f, 1.f, 1.f, 1.f, 1.f, 1.f, 1.f};
    float accB[8] = {1.f, 1.f, 1.f, 1.f, 1.f, 1.f, 1.f, 1.f};
#pragma unroll
    for (int i = 0; i < 6; ++i) {
        int W = PW[i];
        float fxA = fminf(fmaxf((p4A[QI[i]] + 1.0f) * 0.5f * (float)(W - 1), 0.0f), (float)(W - 1));
        float fyA = fminf(fmaxf((p4A[RI[i]] + 1.0f) * 0.5f * 255.0f, 0.0f), 255.0f);
        float x0A = fminf(floorf(fxA), (float)(W - 2));
        float y0A = fminf(floorf(fyA), 254.0f);
        float wxA = fxA - x0A, wyA = fyA - y0A;
        const __half* baseA = a.pl[i] + ((size_t)(int)y0A * W + (int)x0A) * 32 + chA;
        float fxB = fminf(fmaxf((p4B[QI[i]] + 1.0f) * 0.5f * (float)(W - 1), 0.0f), (float)(W - 1));
        float fyB = fminf(fmaxf((p4B[RI[i]] + 1.0f) * 0.5f * 255.0f, 0.0f), 255.0f);
        float x0B = fminf(floorf(fxB), (float)(W - 2));
        float y0B = fminf(floorf(fyB), 254.0f);
        float wxB = fxB - x0B, wyB = fyB - y0B;
        const __half* baseB = a.pl[i] + ((size_t)(int)y0B * W + (int)x0B) * 32 + chB;

        H8 a00, a01, a10, a11, b00, b01, b10, b11;
        a00.f4 = *(const float4*)(baseA);
        a01.f4 = *(const float4*)(baseA + 32);
        a10.f4 = *(const float4*)(baseA + (size_t)W * 32);
        a11.f4 = *(const float4*)(baseA + (size_t)W * 32 + 32);
        b00.f4 = *(const float4*)(baseB);
        b01.f4 = *(const float4*)(baseB + 32);
        b10.f4 = *(const float4*)(baseB + (size_t)W * 32);
        b11.f4 = *(const float4*)(baseB + (size_t)W * 32 + 32);

        float wA00 = (1.f - wyA) * (1.f - wxA), wA01 = (1.f - wyA) * wxA;
        float wA10 = wyA * (1.f - wxA), wA11 = wyA * wxA;
        float wB00 = (1.f - wyB) * (1.f - wxB), wB01 = (1.f - wyB) * wxB;
        float wB10 = wyB * (1.f - wxB), wB11 = wyB * wxB;
#pragma unroll
        for (int k = 0; k < 8; ++k) {
            accA[k] *= wA00 * __half2float(a00.h[k]) + wA01 * __half2float(a01.h[k]) +
                       wA10 * __half2float(a10.h[k]) + wA11 * __half2float(a11.h[k]);
            accB[k] *= wB00 * __half2float(b00.h[k]) + wB01 * __half2float(b01.h[k]) +
                       wB10 * __half2float(b10.h[k]) + wB11 * __half2float(b11.h[k]);
        }
    }
    float* opA = a.out + (size_t)oA * 32 + chA;
    f32x4 vA0 = {accA[0], accA[1], accA[2], accA[3]};
    f32x4 vA1 = {accA[4], accA[5], accA[6], accA[7]};
    __builtin_nontemporal_store(vA0, (f32x4*)(opA));
    __builtin_nontemporal_store(vA1, (f32x4*)(opA + 4));
    if (hasB) {
        float* opB = a.out + (size_t)oB * 32 + chB;
        f32x4 vB0 = {accB[0], accB[1], accB[2], accB[3]};
        f32x4 vB1 = {accB[4], accB[5], accB[6], accB[7]};
        __builtin_nontemporal_store(vB0, (f32x4*)(opB));
        __builtin_nontemporal_store(vB1, (f32x4*)(opB + 4));
    }
}

__global__ __launch_bounds__(256) void k4_sample(SK a) {
    int bid = blockIdx.x, tid = threadIdx.x;
    if (bid < NBIN / BPB) {
        int xcd = bid & 7, g = bid >> 3;    // g in 0..127

#pragma unroll
        for (int bb = 0; bb < BPB; ++bb) {
            int j = g * BPB + bb;                            // 0..511
            int bin = ((j >> 8) << 11) | (xcd << 8) | (j & 255);  // XCD = bits 8..10 (xh,yh,zh)

            i32x4 u0 = __builtin_nontemporal_load((const i32x4*)(a.cum + bin * 8));
            i32x4 u1 = __builtin_nontemporal_load((const i32x4*)(a.cum + bin * 8 + 4));
            int cums[8] = {u0.x, u0.y, u0.z, u0.w, u1.x, u1.y, u1.z, u1.w};
            int n4 = cums[7] * 4;

            for (int l0 = tid; l0 < n4; l0 += 512) {
                int l1 = l0 + 256;
                bool hasB = l1 < n4;
                int lB = hasB ? l1 : l0;

                int sA = l0 >> 2, chA = (l0 & 3) << 3;
                int sB = lB >> 2, chB = (lB & 3) << 3;
                int rA = 0, bsA = 0, rB = 0, bsB = 0;
#pragma unroll
                for (int rr = 0; rr < NREP - 1; ++rr) {
                    if (sA >= cums[rr]) { rA = rr + 1; bsA = cums[rr]; }
                    if (sB >= cums[rr]) { rB = rr + 1; bsB = cums[rr]; }
                }
                size_t slotA = ((size_t)rA * NBIN + bin) * SCAP + (sA - bsA);
                size_t slotB = ((size_t)rB * NBIN + bin) * SCAP + (sB - bsB);
                f32x4 qA = __builtin_nontemporal_load((const f32x4*)(a.binP4 + slotA));
                f32x4 qB = __builtin_nontemporal_load((const f32x4*)(a.binP4 + slotB));
                int oA = __builtin_nontemporal_load(a.binIdx + slotA);
                int oB = __builtin_nontemporal_load(a.binIdx + slotB);
                float p4A[4] = {qA.x, qA.y, qA.z, qA.w};
                float p4B[4] = {qB.x, qB.y, qB.z, qB.w};
                sample_pair(a, p4A, oA, chA, p4B, oB, chB, hasB);
            }
        }
    } else {
        int ov = a.cnt[NREP * NBIN];
        ov = ov < OVCAP ? ov : OVCAP;
        int ov4 = ov * 4;
        for (int l0 = (bid - NBIN / BPB) * 256 + tid; l0 < ov4; l0 += 4096) {
            int l1 = l0 + 2048;
            bool hasB = l1 < ov4;
            int lB = hasB ? l1 : l0;
            int sA = l0 >> 2, chA = (l0 & 3) << 3;
            int sB = lB >> 2, chB = (lB & 3) << 3;
            f32x4 qA = __builtin_nontemporal_load((const f32x4*)(a.ovP4 + sA));
            f32x4 qB = __builtin_nontemporal_load((const f32x4*)(a.ovP4 + sB));
            float p4A[4] = {qA.x, qA.y, qA.z, qA.w};
            float p4B[4] = {qB.x, qB.y, qB.z, qB.w};
            sample_pair(a, p4A, a.ovIdx[sA], chA, p4B, a.ovIdx[sB], chB, hasB);
        }
    }
}

extern "C" void kernel_launch(void* const* d_in, const int* in_sizes, int n_in,
                              void* d_out, int out_size, void* d_ws, size_t ws_size,
                              hipStream_t stream) {
    const int PWt[6] = {256, 256, 64, 256, 64, 64};
    const int Npts = in_sizes[0] / 3;

    char* ws = (char*)d_ws;
    PK a;
    size_t off = 0;
    for (int i = 0; i < 6; ++i) {
        int W = PWt[i], w2 = W / 2;
        a.x1[i] = (float*)(ws + off);      off += (size_t)32 * 128 * w2 * 4;
        a.lo2[i] = (__half*)(ws + off);    off += (size_t)32 * 256 * w2 * 2;
        a.hi2[i] = (__half*)(ws + off);    off += (size_t)32 * 256 * w2 * 2;
        a.planeH[i] = (__half*)(ws + off); off += (size_t)256 * W * 32 * 2;
    }
    off = (off + 15) & ~(size_t)15;
    a.binP4 = (float4*)(ws + off);  off += (size_t)NREP * NBIN * SCAP * 16;
    a.ovP4 = (float4*)(ws + off);   off += (size_t)OVCAP * 16;
    a.binIdx = (int*)(ws + off);    off += (size_t)NREP * NBIN * SCAP * 4;
    a.ovIdx = (int*)(ws + off);     off += (size_t)OVCAP * 4;
    a.cnt = (int*)(ws + off);       off += ((size_t)NREP * NBIN + 1) * 4;
    off = (off + 15) & ~(size_t)15;
    a.cum = (int*)(ws + off);       off += (size_t)NBIN * 8 * 4;

    a.pts = (const float*)d_in[0];
    a.ts = (const float*)d_in[1];
    for (int i = 0; i < 6; ++i) {
        a.yl[i] = (const float*)d_in[2 + 3 * i];
        a.yha[i] = (const float*)d_in[3 + 3 * i];
        a.yhb[i] = (const float*)d_in[4 + 3 * i];
    }
    a.Npts = Npts;

    k1_l1_zero<<<768 + 129, 256, 0, stream>>>(a);
    k2_v2_scatter<<<512 + 1920, 256, 0, stream>>>(a);
    k3_ht<<<1536 + 16, 256, 0, stream>>>(a);

    SK s;
    for (int i = 0; i < 6; ++i) s.pl[i] = a.planeH[i];
    s.binP4 = a.binP4; s.binIdx = a.binIdx; s.cnt = a.cnt; s.cum = a.cum;
    s.ovP4 = a.ovP4; s.ovIdx = a.ovIdx;
    s.out = (float*)d_out;
    k4_sample<<<NBIN / BPB + 8, 256, 0, stream>>>(s);
}

// Round 8
// 249.671 us; speedup vs baseline: 1.1151x; 1.1151x over previous
//
#include <hip/hip_runtime.h>
#include <hip/hip_fp16.h>

#define NBIN 4096
#define NREP 8        // bin replicas (XCD-aligned via bid&7)
#define SCAP 32       // capacity per replica sub-bin (8*32 = 256 total per bin)
#define OVCAP 65536
#define BPB 4         // bins per k4 block

// coif4 decomposition low-pass filter (24 taps). REC_LO[k]=DEC_LO[23-k], REC_HI[k]=(-1)^k*DEC_LO[k]
__device__ __constant__ float DEC_LO[24] = {
    -1.7849850030882614e-06f, -3.2596802368833675e-06f, 3.1229875865345646e-05f,
    6.233903446100713e-05f, -0.00025997455248771324f, -0.0005890207562443383f,
    0.0012665619292989445f, 0.003751436157278457f, -0.00565828668661072f,
    -0.015211731527946259f, 0.025082261844864097f, 0.03933442712333749f,
    -0.09622044203398798f, -0.06662747426342504f, 0.4343860564914685f,
    0.782238930920499f, 0.41530840703043026f, -0.05607731331675481f,
    -0.08126669968087875f, 0.026682300156053072f, 0.016068943964776348f,
    -0.0073461663276420935f, -0.0016294920126017326f, 0.0008923136685823146f
};

struct PK {
    const float* yl[6];
    const float* yhb[6];   // [C][3][64][w4]
    const float* yha[6];   // [C][3][128][w2]
    float* x1[6];          // [C][128][w2] fp32
    __half* lo2[6];        // [C][256][w2] fp16
    __half* hi2[6];
    __half* planeH[6];     // [256][W][32] fp16 channel-last
    const float* pts;
    const float* ts;
    int* cnt;              // [NREP][NBIN] + ovCnt at cnt[NREP*NBIN]
    int* cum;              // [NBIN][8] cumulative clamped counts (filled by k3)
    float4* binP4;         // [NREP][NBIN][SCAP]
    int* binIdx;           // [NREP][NBIN][SCAP]
    float4* ovP4;          // [OVCAP]
    int* ovIdx;
    int Npts;
};

__device__ __forceinline__ void compute_p4(const float* pts, const float* ts, int p, float* p4) {
    const float sc = (float)(2.0 / (-2.0 * 1.3));
    p4[0] = (pts[p * 3 + 0] - 1.3f) * sc - 1.0f;
    p4[1] = (pts[p * 3 + 1] - 1.3f) * sc - 1.0f;
    p4[2] = (pts[p * 3 + 2] - 1.3f) * sc - 1.0f;
    p4[3] = ts[p] * 2.0f - 1.0f;
}

__device__ __forceinline__ int morton_key(const float* p4) {
    int key = 0;
#pragma unroll
    for (int d = 0; d < 4; ++d) {
        float u = (p4[d] + 1.0f) * 0.5f * 8.0f;
        int ci = (int)u;
        ci = ci < 0 ? 0 : (ci > 7 ? 7 : ci);
#pragma unroll
        for (int b = 0; b < 3; ++b) key |= ((ci >> b) & 1) << (b * 4 + d);
    }
    return key;
}

// ============ K1: idwt level-1 (blocks 0..767) || zero counters (768..896) ========
__global__ __launch_bounds__(256) void k1_l1_zero(PK a) {
    __shared__ struct { float lo[32 * 64], hi[32 * 64]; } sm;
    int bid = blockIdx.x, tid = threadIdx.x;

    if (bid < 768) {
        int rg = bid & 3, c = (bid >> 2) & 31, i = bid >> 7;
        int w4 = (i == 0 || i == 1 || i == 3) ? 64 : 16;
        int lw4 = (w4 == 64) ? 6 : 4;

        const float* llc = a.yl[i] + (size_t)c * 64 * w4;
        const float* lhc = a.yhb[i] + (size_t)(c * 3 + 0) * 64 * w4;
        const float* hlc = a.yhb[i] + (size_t)(c * 3 + 1) * 64 * w4;
        const float* hhc = a.yhb[i] + (size_t)(c * 3 + 2) * 64 * w4;

        for (int idx = tid; idx < (16 << lw4); idx += 256) {
            int mp = idx >> lw4, x = idx & (w4 - 1);
            int m = rg * 16 + mp;
            float lo0 = 0.f, lo1 = 0.f, hi0 = 0.f, hi1 = 0.f;
#pragma unroll
            for (int j = 0; j < 12; ++j) {
                int r = (m - j) & 63;
                int ii = (r << lw4) + x;
                float vll = llc[ii], vlh = lhc[ii], vhl = hlc[ii], vhh = hhc[ii];
                float rl0 = DEC_LO[23 - 2 * j], rl1 = DEC_LO[22 - 2 * j];
                float rh0 = DEC_LO[2 * j],      rh1 = -DEC_LO[2 * j + 1];
                lo0 += rl0 * vll + rh0 * vlh;
                lo1 += rl1 * vll + rh1 * vlh;
                hi0 += rl0 * vhl + rh0 * vhh;
                hi1 += rl1 * vhl + rh1 * vhh;
            }
            sm.lo[((2 * mp) << lw4) + x] = lo0;
            sm.lo[((2 * mp + 1) << lw4) + x] = lo1;
            sm.hi[((2 * mp) << lw4) + x] = hi0;
            sm.hi[((2 * mp + 1) << lw4) + x] = hi1;
        }
        __syncthreads();

        int w2 = w4 * 2;
        float* x1p = a.x1[i] + (size_t)c * 128 * w2;
        for (int idx = tid; idx < (32 << lw4); idx += 256) {
            int yl = idx >> lw4, mcol = idx & (w4 - 1);
            float o0 = 0.f, o1 = 0.f;
#pragma unroll
            for (int j = 0; j < 12; ++j) {
                int r = (mcol - j) & (w4 - 1);
                float vl = sm.lo[(yl << lw4) + r], vh = sm.hi[(yl << lw4) + r];
                o0 += DEC_LO[23 - 2 * j] * vl + DEC_LO[2 * j] * vh;
                o1 += DEC_LO[22 - 2 * j] * vl - DEC_LO[2 * j + 1] * vh;
            }
            *(float2*)(x1p + (size_t)(rg * 32 + yl) * w2 + 2 * mcol) = make_float2(o0, o1);
        }
    } else {
        int idx = (bid - 768) * 256 + tid;
        if (idx <= NREP * NBIN) a.cnt[idx] = 0;   // 8*4096 replica counters + ovCnt
    }
}

// ============ K2: replica scatter (0..511) || idwt level-2 vertical (512..2431, 4 x-outputs/thread, XCD-swizzled) ==========
__global__ __launch_bounds__(256) void k2_v2_scatter(PK a) {
    int bid = blockIdx.x, tid = threadIdx.x;

    if (bid < 512) {
        // Single-pass scatter into replica sub-bins: replica = bid&7 aligns all
        // writers of a given counter/data line to one XCD and cuts per-line
        // atomic serialization 8x. 4-pt batching overlaps atomic latencies.
        // Plain stores: L2 absorbs/merges the scattered 16B writes (NT regressed).
        const int S = 512 * 256;  // 131072 threads
        int rep = bid & 7;
        int t = bid * 256 + tid;
        for (int base = 0; base < a.Npts; base += 4 * S) {
            float4 q[4];
            int key[4], pi[4], pos[4];
#pragma unroll
            for (int k = 0; k < 4; ++k) {
                int p = base + t + k * S;
                pi[k] = p;
                if (p < a.Npts) {
                    float p4[4];
                    compute_p4(a.pts, a.ts, p, p4);
                    key[k] = morton_key(p4);
                    q[k] = make_float4(p4[0], p4[1], p4[2], p4[3]);
                } else {
                    key[k] = -1;
                }
            }
#pragma unroll
            for (int k = 0; k < 4; ++k)
                if (key[k] >= 0) pos[k] = atomicAdd(&a.cnt[rep * NBIN + key[k]], 1);
#pragma unroll
            for (int k = 0; k < 4; ++k) {
                if (key[k] < 0) continue;
                if (pos[k] < SCAP) {
                    size_t slot = ((size_t)rep * NBIN + key[k]) * SCAP + pos[k];
                    a.binP4[slot] = q[k];
                    a.binIdx[slot] = pi[k];
                } else {
                    int ov = atomicAdd(&a.cnt[NREP * NBIN], 1);
                    if (ov < OVCAP) {
                        a.ovP4[ov] = q[k];
                        a.ovIdx[ov] = pi[k];
                    }
                }
            }
        }
    } else {
        int ib = bid - 512;                 // 0..1919
        ib = (ib & 7) * 240 + (ib >> 3);    // XCD chunk swizzle (bijective: 1920 % 8 == 0)

        const int boff[7] = {0, 512, 1024, 1152, 1664, 1792, 1920};
        int i = 0;
        while (i < 5 && ib >= boff[i + 1]) ++i;
        int lw2 = (i == 0 || i == 1 || i == 3) ? 7 : 5;
        int w2 = 1 << lw2;
        unsigned t = (unsigned)(ib - boff[i]) * 256u + tid;
        unsigned tpc = 32u << lw2;          // threads per channel (w2/4 x-quads * 128 rows)
        unsigned c = t >> (5 + lw2);
        unsigned rem = t & (tpc - 1);
        unsigned m = rem >> (lw2 - 2);
        unsigned x = (rem & (unsigned)((w2 >> 2) - 1)) * 4;
        unsigned hw = 128u << lw2;

        const float* llc = a.x1[i] + (size_t)c * hw;
        const float* lhc = a.yha[i] + (size_t)(c * 3 + 0) * hw;
        const float* hlc = a.yha[i] + (size_t)(c * 3 + 1) * hw;
        const float* hhc = a.yha[i] + (size_t)(c * 3 + 2) * hw;

        float4 acl0 = {0,0,0,0}, acl1 = {0,0,0,0}, ach0 = {0,0,0,0}, ach1 = {0,0,0,0};
#pragma unroll
        for (int j = 0; j < 12; ++j) {
            int r = ((int)m - j) & 127;
            unsigned idx = ((unsigned)r << lw2) + x;
            float4 vll = *(const float4*)(llc + idx);
            float4 vlh = *(const float4*)(lhc + idx);
            float4 vhl = *(const float4*)(hlc + idx);
            float4 vhh = *(const float4*)(hhc + idx);
            float rl0 = DEC_LO[23 - 2 * j], rl1 = DEC_LO[22 - 2 * j];
            float rh0 = DEC_LO[2 * j],      rh1 = -DEC_LO[2 * j + 1];
            acl0.x += rl0 * vll.x + rh0 * vlh.x;  acl0.y += rl0 * vll.y + rh0 * vlh.y;
            acl0.z += rl0 * vll.z + rh0 * vlh.z;  acl0.w += rl0 * vll.w + rh0 * vlh.w;
            acl1.x += rl1 * vll.x + rh1 * vlh.x;  acl1.y += rl1 * vll.y + rh1 * vlh.y;
            acl1.z += rl1 * vll.z + rh1 * vlh.z;  acl1.w += rl1 * vll.w + rh1 * vlh.w;
            ach0.x += rl0 * vhl.x + rh0 * vhh.x;  ach0.y += rl0 * vhl.y + rh0 * vhh.y;
            ach0.z += rl0 * vhl.z + rh0 * vhh.z;  ach0.w += rl0 * vhl.w + rh0 * vhh.w;
            ach1.x += rl1 * vhl.x + rh1 * vhh.x;  ach1.y += rl1 * vhl.y + rh1 * vhh.y;
            ach1.z += rl1 * vhl.z + rh1 * vhh.z;  ach1.w += rl1 * vhl.w + rh1 * vhh.w;
        }
        size_t ob = ((size_t)c * 256 + 2 * m) * w2 + x;
        __half* lp = a.lo2[i] + ob;
        *(__half2*)(lp)          = __floats2half2_rn(acl0.x, acl0.y);
        *(__half2*)(lp + 2)      = __floats2half2_rn(acl0.z, acl0.w);
        *(__half2*)(lp + w2)     = __floats2half2_rn(acl1.x, acl1.y);
        *(__half2*)(lp + w2 + 2) = __floats2half2_rn(acl1.z, acl1.w);
        __half* hpp = a.hi2[i] + ob;
        *(__half2*)(hpp)          = __floats2half2_rn(ach0.x, ach0.y);
        *(__half2*)(hpp + 2)      = __floats2half2_rn(ach0.z, ach0.w);
        *(__half2*)(hpp + w2)     = __floats2half2_rn(ach1.x, ach1.y);
        *(__half2*)(hpp + w2 + 2) = __floats2half2_rn(ach1.z, ach1.w);
    }
}

// ============ K3: idwt l2 horizontal + transpose (0..1535) || cum-prefix table (1536..1551) ========
__global__ __launch_bounds__(256) void k3_ht(PK a) {
    __shared__ struct { __half lo[32 * 130], hi[32 * 130]; } sm;
    int bid = blockIdx.x, tid = threadIdx.x;

    if (bid < 1536) {
        int i = bid >> 8, y = bid & 255;
        int lw2 = (i == 0 || i == 1 || i == 3) ? 7 : 5;
        int w2 = 1 << lw2;
        int stride = w2 + 2;  // fp16 LDS: conflict-free column reads

        for (int idx = tid; idx < (32 << lw2); idx += 256) {
            int c = idx >> lw2, x = idx & (w2 - 1);
            size_t g = ((size_t)c * 256 + y) * w2 + x;
            sm.lo[c * stride + x] = a.lo2[i][g];
            sm.hi[c * stride + x] = a.hi2[i][g];
        }
        __syncthreads();

        int W = 2 * w2;
        __half* orow = a.planeH[i] + (size_t)y * W * 32;
        for (int idx = tid; idx < (32 << lw2); idx += 256) {
            int m = idx >> 5, c = idx & 31;
            float o0 = 0.f, o1 = 0.f;
#pragma unroll
            for (int j = 0; j < 12; ++j) {
                int r2 = m - j; if (r2 < 0) r2 += w2;
                float vl = __half2float(sm.lo[c * stride + r2]);
                float vh = __half2float(sm.hi[c * stride + r2]);
                o0 += DEC_LO[23 - 2 * j] * vl + DEC_LO[2 * j] * vh;
                o1 += DEC_LO[22 - 2 * j] * vl - DEC_LO[2 * j + 1] * vh;
            }
            orow[(2 * m) * 32 + c] = __float2half(o0);
            orow[(2 * m + 1) * 32 + c] = __float2half(o1);
        }
    } else {
        // Compact the 8 scattered replica counters per bin into a contiguous
        // cumulative table: k4 then needs 2 coalesced int4 loads, not 8
        // scattered 4B loads 16KB apart.
        int bin = (bid - 1536) * 256 + tid;
        int c = 0;
#pragma unroll
        for (int r = 0; r < NREP; ++r) {
            int v = a.cnt[r * NBIN + bin];
            c += (v < SCAP ? v : SCAP);
            a.cum[bin * 8 + r] = c;
        }
    }
}

// ============ K4: sampling, 4 bins/block (1024 blocks) + 8 overflow blocks.
// XCD selector = bin bits 8..10 (x_hi,y_hi,z_hi): per-XCD texel footprint ~4.6MB < 4MB-ish L2
// (vs 6MB for the Morton-chunk selector) — the verified FETCH win from R7, minus the NT poison.
union H8 { float4 f4; __half h[8]; };

struct SK {
    const __half* pl[6];
    const float4* binP4;
    const int* binIdx;
    const int* cnt;
    const int* cum;
    const float4* ovP4;
    const int* ovIdx;
    float* out;
};

// Two points' samples interleaved per plane: 8 independent 16B loads in flight
// per step — doubles per-thread MLP on the latency-critical path.
__device__ __forceinline__ void sample_pair(const SK& a,
        const float* p4A, int oA, int chA,
        const float* p4B, int oB, int chB, bool hasB) {
    const int PW[6] = {256, 256, 64, 256, 64, 64};
    const int QI[6] = {0, 0, 3, 1, 3, 3};
    const int RI[6] = {1, 2, 0, 2, 1, 2};
    float accA[8] = {1.f, 1.f, 1.f, 1.f, 1.f, 1.f, 1.f, 1.f};
    float accB[8] = {1.f, 1.f, 1.f, 1.f, 1.f, 1.f, 1.f, 1.f};
#pragma unroll
    for (int i = 0; i < 6; ++i) {
        int W = PW[i];
        float fxA = fminf(fmaxf((p4A[QI[i]] + 1.0f) * 0.5f * (float)(W - 1), 0.0f), (float)(W - 1));
        float fyA = fminf(fmaxf((p4A[RI[i]] + 1.0f) * 0.5f * 255.0f, 0.0f), 255.0f);
        float x0A = fminf(floorf(fxA), (float)(W - 2));
        float y0A = fminf(floorf(fyA), 254.0f);
        float wxA = fxA - x0A, wyA = fyA - y0A;
        const __half* baseA = a.pl[i] + ((size_t)(int)y0A * W + (int)x0A) * 32 + chA;
        float fxB = fminf(fmaxf((p4B[QI[i]] + 1.0f) * 0.5f * (float)(W - 1), 0.0f), (float)(W - 1));
        float fyB = fminf(fmaxf((p4B[RI[i]] + 1.0f) * 0.5f * 255.0f, 0.0f), 255.0f);
        float x0B = fminf(floorf(fxB), (float)(W - 2));
        float y0B = fminf(floorf(fyB), 254.0f);
        float wxB = fxB - x0B, wyB = fyB - y0B;
        const __half* baseB = a.pl[i] + ((size_t)(int)y0B * W + (int)x0B) * 32 + chB;

        H8 a00, a01, a10, a11, b00, b01, b10, b11;
        a00.f4 = *(const float4*)(baseA);
        a01.f4 = *(const float4*)(baseA + 32);
        a10.f4 = *(const float4*)(baseA + (size_t)W * 32);
        a11.f4 = *(const float4*)(baseA + (size_t)W * 32 + 32);
        b00.f4 = *(const float4*)(baseB);
        b01.f4 = *(const float4*)(baseB + 32);
        b10.f4 = *(const float4*)(baseB + (size_t)W * 32);
        b11.f4 = *(const float4*)(baseB + (size_t)W * 32 + 32);

        float wA00 = (1.f - wyA) * (1.f - wxA), wA01 = (1.f - wyA) * wxA;
        float wA10 = wyA * (1.f - wxA), wA11 = wyA * wxA;
        float wB00 = (1.f - wyB) * (1.f - wxB), wB01 = (1.f - wyB) * wxB;
        float wB10 = wyB * (1.f - wxB), wB11 = wyB * wxB;
#pragma unroll
        for (int k = 0; k < 8; ++k) {
            accA[k] *= wA00 * __half2float(a00.h[k]) + wA01 * __half2float(a01.h[k]) +
                       wA10 * __half2float(a10.h[k]) + wA11 * __half2float(a11.h[k]);
            accB[k] *= wB00 * __half2float(b00.h[k]) + wB01 * __half2float(b01.h[k]) +
                       wB10 * __half2float(b10.h[k]) + wB11 * __half2float(b11.h[k]);
        }
    }
    float* opA = a.out + (size_t)oA * 32 + chA;
    *(float4*)(opA)     = make_float4(accA[0], accA[1], accA[2], accA[3]);
    *(float4*)(opA + 4) = make_float4(accA[4], accA[5], accA[6], accA[7]);
    if (hasB) {
        float* opB = a.out + (size_t)oB * 32 + chB;
        *(float4*)(opB)     = make_float4(accB[0], accB[1], accB[2], accB[3]);
        *(float4*)(opB + 4) = make_float4(accB[4], accB[5], accB[6], accB[7]);
    }
}

__global__ __launch_bounds__(256) void k4_sample(SK a) {
    int bid = blockIdx.x, tid = threadIdx.x;
    if (bid < NBIN / BPB) {
        int xcd = bid & 7, g = bid >> 3;    // g in 0..127

#pragma unroll
        for (int bb = 0; bb < BPB; ++bb) {
            int j = g * BPB + bb;                                 // 0..511
            int bin = ((j >> 8) << 11) | (xcd << 8) | (j & 255);  // XCD = bits 8..10 (x_hi,y_hi,z_hi)

            int4 u0 = *(const int4*)(a.cum + bin * 8);
            int4 u1 = *(const int4*)(a.cum + bin * 8 + 4);
            int cums[8] = {u0.x, u0.y, u0.z, u0.w, u1.x, u1.y, u1.z, u1.w};
            int n4 = cums[7] * 4;

            for (int l0 = tid; l0 < n4; l0 += 512) {
                int l1 = l0 + 256;
                bool hasB = l1 < n4;
                int lB = hasB ? l1 : l0;

                int sA = l0 >> 2, chA = (l0 & 3) << 3;
                int sB = lB >> 2, chB = (lB & 3) << 3;
                int rA = 0, bsA = 0, rB = 0, bsB = 0;
#pragma unroll
                for (int rr = 0; rr < NREP - 1; ++rr) {
                    if (sA >= cums[rr]) { rA = rr + 1; bsA = cums[rr]; }
                    if (sB >= cums[rr]) { rB = rr + 1; bsB = cums[rr]; }
                }
                size_t slotA = ((size_t)rA * NBIN + bin) * SCAP + (sA - bsA);
                size_t slotB = ((size_t)rB * NBIN + bin) * SCAP + (sB - bsB);
                float4 qA = a.binP4[slotA];
                float4 qB = a.binP4[slotB];
                int oA = a.binIdx[slotA];
                int oB = a.binIdx[slotB];
                float p4A[4] = {qA.x, qA.y, qA.z, qA.w};
                float p4B[4] = {qB.x, qB.y, qB.z, qB.w};
                sample_pair(a, p4A, oA, chA, p4B, oB, chB, hasB);
            }
        }
    } else {
        int ov = a.cnt[NREP * NBIN];
        ov = ov < OVCAP ? ov : OVCAP;
        int ov4 = ov * 4;
        for (int l0 = (bid - NBIN / BPB) * 256 + tid; l0 < ov4; l0 += 4096) {
            int l1 = l0 + 2048;
            bool hasB = l1 < ov4;
            int lB = hasB ? l1 : l0;
            int sA = l0 >> 2, chA = (l0 & 3) << 3;
            int sB = lB >> 2, chB = (lB & 3) << 3;
            float4 qA = a.ovP4[sA];
            float4 qB = a.ovP4[sB];
            float p4A[4] = {qA.x, qA.y, qA.z, qA.w};
            float p4B[4] = {qB.x, qB.y, qB.z, qB.w};
            sample_pair(a, p4A, a.ovIdx[sA], chA, p4B, a.ovIdx[sB], chB, hasB);
        }
    }
}

extern "C" void kernel_launch(void* const* d_in, const int* in_sizes, int n_in,
                              void* d_out, int out_size, void* d_ws, size_t ws_size,
                              hipStream_t stream) {
    const int PWt[6] = {256, 256, 64, 256, 64, 64};
    const int Npts = in_sizes[0] / 3;

    char* ws = (char*)d_ws;
    PK a;
    size_t off = 0;
    for (int i = 0; i < 6; ++i) {
        int W = PWt[i], w2 = W / 2;
        a.x1[i] = (float*)(ws + off);      off += (size_t)32 * 128 * w2 * 4;
        a.lo2[i] = (__half*)(ws + off);    off += (size_t)32 * 256 * w2 * 2;
        a.hi2[i] = (__half*)(ws + off);    off += (size_t)32 * 256 * w2 * 2;
        a.planeH[i] = (__half*)(ws + off); off += (size_t)256 * W * 32 * 2;
    }
    off = (off + 15) & ~(size_t)15;
    a.binP4 = (float4*)(ws + off);  off += (size_t)NREP * NBIN * SCAP * 16;
    a.ovP4 = (float4*)(ws + off);   off += (size_t)OVCAP * 16;
    a.binIdx = (int*)(ws + off);    off += (size_t)NREP * NBIN * SCAP * 4;
    a.ovIdx = (int*)(ws + off);     off += (size_t)OVCAP * 4;
    a.cnt = (int*)(ws + off);       off += ((size_t)NREP * NBIN + 1) * 4;
    off = (off + 15) & ~(size_t)15;
    a.cum = (int*)(ws + off);       off += (size_t)NBIN * 8 * 4;

    a.pts = (const float*)d_in[0];
    a.ts = (const float*)d_in[1];
    for (int i = 0; i < 6; ++i) {
        a.yl[i] = (const float*)d_in[2 + 3 * i];
        a.yha[i] = (const float*)d_in[3 + 3 * i];
        a.yhb[i] = (const float*)d_in[4 + 3 * i];
    }
    a.Npts = Npts;

    k1_l1_zero<<<768 + 129, 256, 0, stream>>>(a);
    k2_v2_scatter<<<512 + 1920, 256, 0, stream>>>(a);
    k3_ht<<<1536 + 16, 256, 0, stream>>>(a);

    SK s;
    for (int i = 0; i < 6; ++i) s.pl[i] = a.planeH[i];
    s.binP4 = a.binP4; s.binIdx = a.binIdx; s.cnt = a.cnt; s.cum = a.cum;
    s.ovP4 = a.ovP4; s.ovIdx = a.ovIdx;
    s.out = (float*)d_out;
    k4_sample<<<NBIN / BPB + 8, 256, 0, stream>>>(s);
}